// Round 1
// 2253.390 us; speedup vs baseline: 1.6485x; 1.6485x over previous
//
#include <hip/hip_runtime.h>
#include <math.h>

#define B_   32
#define T_   64
#define N_   128
#define D_   64
#define C_   129
#define CK_  16
#define H_   2
#define QD_  5
#define PLM_ 768

typedef _Float16 h2v __attribute__((ext_vector_type(2)));
typedef _Float16 h4v __attribute__((ext_vector_type(4)));
typedef _Float16 h8  __attribute__((ext_vector_type(8)));
typedef float    f4  __attribute__((ext_vector_type(4)));

// ---- workspace layout (float/u32 slots) ----
constexpr int OFF_QV   = 0;                           // 640
constexpr int OFF_BE   = 640;                         // fp32 3*128*64
constexpr int OFF_WB2  = OFF_BE + 3*128*64;           // h2v 3*128*65*64 gate weights [g][n][c2][o], pair over c'
constexpr int OFF_VWB2 = OFF_WB2 + 3*128*65*64;       // (dead) h2v 2*65*132
constexpr int OFF_QKB2 = OFF_VWB2 + 2*65*132;         // h2v 4*65*16    qkW [qk*2+h][c2][ck], pair over comb-c
constexpr int OFF_ATTB = OFF_QKB2 + 4*65*16;          // (dead) fp32 132
constexpr int OFF_VTO  = OFF_ATTB + 132;              // fp32 B*N
constexpr int OFF_H    = OFF_VTO + B_*N_;             // fp32 2*B*N*64 double-buffered h exchange
constexpr int OFF_CNT  = OFF_H + 2*B_*N_*64;          // u32 x32 barrier counters (memset 0 per launch)
constexpr int OFF_VWB3 = OFF_CNT + 32;                // f16 9*9*64*8 att-GEMM B-fragments (frag-major)

#if __has_builtin(__builtin_amdgcn_fdot2)
__device__ __forceinline__ float fdot2(h2v a, h2v b, float c) {
    return __builtin_amdgcn_fdot2(a, b, c, false);
}
#else
__device__ __forceinline__ float fdot2(h2v a, h2v b, float c) {
    return c + (float)a.x*(float)b.x + (float)a.y*(float)b.y;
}
#endif

// ---------------- precompute kernels ----------------

__global__ void k_qv(const float* __restrict__ plm, const float* __restrict__ W1,
                     const float* __restrict__ b1, const float* __restrict__ W2,
                     const float* __restrict__ b2, float* __restrict__ ws) {
    int n = blockIdx.x, j = threadIdx.x;          // 128 x 128
    __shared__ float hid[128];
    float acc = b1[j];
    for (int p = 0; p < PLM_; ++p) acc += plm[n*PLM_ + p] * W1[p*128 + j];
    hid[j] = fmaxf(acc, 0.f);
    __syncthreads();
    if (j < QD_) {
        float a = b2[j];
        for (int q = 0; q < 128; ++q) a += hid[q] * W2[q*QD_ + j];
        ws[OFF_QV + n*QD_ + j] = a;
    }
}

// WB2[g][n][c2][o] = h2v( Weff[c'=2c2][o], Weff[2c2+1][o] );  BE[g][n][o]
__global__ void k_weff(const float* __restrict__ rW, const float* __restrict__ uW,
                       const float* __restrict__ cW, const float* __restrict__ rb,
                       const float* __restrict__ ub, const float* __restrict__ cb,
                       float* __restrict__ ws) {
    int g = blockIdx.x >> 7, n = blockIdx.x & 127;   // 384 blocks x 256 thr
    const float* W  = (g == 0) ? rW : (g == 1) ? uW : cW;
    const float* bb = (g == 0) ? rb : (g == 1) ? ub : cb;
    float qn[QD_];
#pragma unroll
    for (int q = 0; q < QD_; ++q) qn[q] = ws[OFF_QV + n*QD_ + q];
    h2v* WB = (h2v*)(ws + OFF_WB2);
    for (int idx = threadIdx.x; idx < 65*64; idx += 256) {
        int c2 = idx >> 6, o = idx & 63;
        float w0 = 0.f, w1 = 0.f;
#pragma unroll
        for (int q = 0; q < QD_; ++q) w0 += qn[q] * W[(q*C_ + 2*c2)*D_ + o];
        if (2*c2 + 1 < C_) {
#pragma unroll
            for (int q = 0; q < QD_; ++q) w1 += qn[q] * W[(q*C_ + 2*c2 + 1)*D_ + o];
        }
        WB[((g*128 + n)*65 + c2)*64 + o] = h2v{(_Float16)w0, (_Float16)w1};
    }
    if (threadIdx.x < D_) {
        int o = threadIdx.x;
        float acc = 0.f;
#pragma unroll
        for (int q = 0; q < QD_; ++q) acc += qn[q] * bb[q*D_ + o];
        ws[OFF_BE + (g*128 + n)*D_ + o] = acc;
    }
}

// QKB2[qk*2+h][c2][ck] (pair over comb-c); VWB3 att-GEMM B fragments.
// VWB3 frag (nt,kt): lane l elem j = B[k=kt*32+(l>>4)*8+j][n=nt*16+(l&15)]
//   B[k][n] = 0.5*vW[h=k/132][c=k%132][n]  (k<264, c<129, n<129)
//   B[264][n] = 0.5*(vb0[n]+vb1[n]);  else 0.
__global__ void k_pack(const float* __restrict__ vW, const float* __restrict__ qW,
                       const float* __restrict__ kW, const float* __restrict__ vb,
                       float* __restrict__ ws) {
    int stride = gridDim.x * blockDim.x;
    int t0 = blockIdx.x * blockDim.x + threadIdx.x;
    h2v* QKB = (h2v*)(ws + OFF_QKB2);
    for (int idx = t0; idx < 4*65*16; idx += stride) {
        int g = idx / (65*16), r = idx % (65*16);
        int qk = g >> 1, h = g & 1;
        int c2 = r / 16, ck = r % 16;
        const float* src = qk ? kW : qW;
        float w0 = src[(h*C_ + 2*c2)*CK_ + ck];
        float w1 = (2*c2 + 1 < C_) ? src[(h*C_ + 2*c2 + 1)*CK_ + ck] : 0.f;
        QKB[idx] = h2v{(_Float16)w0, (_Float16)w1};
    }
    _Float16* VB = (_Float16*)(ws + OFF_VWB3);
    for (int idx = t0; idx < 9*9*64*8; idx += stride) {
        int j  = idx & 7;
        int l  = (idx >> 3) & 63;
        int rest = idx >> 9;           // nt*9 + kt
        int kt = rest % 9, nt = rest / 9;
        int k = kt*32 + (l >> 4)*8 + j;
        int n = nt*16 + (l & 15);
        float v = 0.f;
        if (n < C_) {
            if (k < 264) {
                int h = k / 132, c = k % 132;
                if (c < C_) v = 0.5f * vW[(h*C_ + c)*C_ + n];
            } else if (k == 264) {
                v = 0.5f * (vb[n] + vb[C_ + n]);
            }
        }
        VB[idx] = (_Float16)v;
    }
}

__global__ void k_vto(const float* __restrict__ mask, float* __restrict__ ws) {
    int idx = blockIdx.x * blockDim.x + threadIdx.x;
    if (idx < B_*N_) {
        int b = idx >> 7, n = idx & 127;
        float acc = 0.f;
        for (int t = 0; t < T_; ++t) acc += mask[(b*T_ + t)*N_ + n];
        ws[OFF_VTO + idx] = acc;
    }
}

// ---------------- main recurrent kernel ----------------
// 256 blocks x 1024 threads, cooperative (co-residency only, NO grid.sync).
// block = (b = blk>>3, ng = blk&7 : 16 nodes). Only h crosses blocks.
// z (P@comb) and att (z@vW) run on MFMA 16x16x32 f16; rest on VALU.
__global__ void __launch_bounds__(1024, 4) k_main(
    const float* __restrict__ obs, const float* __restrict__ mask,
    const float* __restrict__ avg, const int* __restrict__ lengths,
    const float* __restrict__ qb, const float* __restrict__ kb,
    float* __restrict__ ws, float* __restrict__ out) {
    const int tid = threadIdx.x;
    const int b  = blockIdx.x >> 3;
    const int ng = blockIdx.x & 7;
    const int n0 = ng * 16;

    // LDS: 36864 + 8704 + 10368 + 512 + 4096 = 60544 B  (< 64 KB)
    __shared__ __align__(16) _Float16 comball[128*144]; // [j][c]: 0..63 obs,64 rar,65..128 h,129..143 pad0
    __shared__ __align__(16) char regA[8704];  // sPH f16[32][136] -> { attF f16[16][136] @0 | h1L f32[16*66] @4352 }
    __shared__ __align__(16) char regB[10368]; // kall f16[2*128*18] @0 + qf f16[2*16*18] @9216 -> z_lds f16[16][296] -> candin h2v[16*66]
    __shared__ float maskL[128];
    __shared__ float h_own[16*64];

    _Float16* sPH    = (_Float16*)regA;              // [32][136]
    _Float16* attF   = (_Float16*)regA;              // [16][136]
    float*    h1L    = (float*)(regA + 4352);        // [16][66]
    _Float16* kall   = (_Float16*)regB;              // [2*128][18]
    _Float16* qfH    = (_Float16*)(regB + 9216);     // [2*16][18]
    _Float16* z_lds  = (_Float16*)regB;              // [16][296]: cols 0..263 z, 264 bias=1, 265..287 zero
    h2v*      candin = (h2v*)regB;                   // [16][66]

    float* Hx = ws + OFF_H;
    unsigned* CNT = (unsigned*)(ws + OFF_CNT);
    const h2v* QKB = (const h2v*)(ws + OFF_QKB2);
    const h2v* WB  = (const h2v*)(ws + OFF_WB2);
    const h8*  VB3 = (const h8*)(ws + OFF_VWB3);

    for (int i = tid; i < 16*64; i += 1024) h_own[i] = 0.f;
    for (int i = tid; i < 128*15; i += 1024)                  // zero pad cols 129..143
        comball[(i/15)*144 + 129 + (i%15)] = (_Float16)0.f;
    const int lenb = lengths[b];
    __syncthreads();

    for (int t = 0; t < T_; ++t) {
        // ---- P0: barrier + import h ----
        if (t > 0) {
            if (tid == 0) {
                unsigned target = 8u * (unsigned)t;
                while (__hip_atomic_load(&CNT[b], __ATOMIC_RELAXED,
                                         __HIP_MEMORY_SCOPE_AGENT) < target)
                    __builtin_amdgcn_s_sleep(2);
            }
            __syncthreads();
            const float* Hr = Hx + (size_t)((t & 1)*B_ + b)*N_*64;
#pragma unroll
            for (int p = 0; p < 8; ++p) {
                int idx = tid + p*1024;
                int j = idx >> 6, d = idx & 63;
                float hv = ((j >> 4) == ng) ? h_own[(j & 15)*64 + d]
                         : __hip_atomic_load((float*)Hr + idx, __ATOMIC_RELAXED,
                                             __HIP_MEMORY_SCOPE_AGENT);
                comball[j*144 + 65 + d] = (_Float16)hv;
            }
        } else {
#pragma unroll
            for (int p = 0; p < 8; ++p) {
                int idx = tid + p*1024;
                comball[(idx >> 6)*144 + 65 + (idx & 63)] = (_Float16)0.f;
            }
        }
        // ---- P1: x-part ----
        {
            const float* obsR = obs + (size_t)(b*T_ + t)*N_*D_;
#pragma unroll
            for (int p = 0; p < 8; ++p) {
                int idx = tid + p*1024;
                comball[(idx >> 6)*144 + (idx & 63)] = (_Float16)obsR[idx];
            }
            if (tid < 128) {
                maskL[tid] = mask[(b*T_ + t)*N_ + tid];
                float a = avg[(b*T_ + t)*N_ + tid];
                comball[tid*144 + 64] =
                    (_Float16)(0.5f * tanhf(a / (ws[OFF_VTO + b*N_ + tid] + 1.f)));
            }
        }
        __syncthreads();
        // ---- P2: q for own 16 nodes (512 threads) ----
        if (tid < 512) {
            int ck = tid & 15, i = (tid >> 4) & 15, h = tid >> 8;
            const h2v* Wq = QKB + (h*65)*16 + ck;
            const h2v* cbj = (const h2v*)(comball + (n0 + i)*144);
            float acc = qb[h*CK_ + ck];
#pragma unroll 13
            for (int c2 = 0; c2 < 65; ++c2) acc = fdot2(cbj[c2], Wq[c2*16], acc);
            qfH[(h*16 + i)*18 + ck] = (_Float16)acc;
        }
        // ---- P3: k for ALL 128 nodes (4 j per thread) ----
        {
            int ck = tid & 15, jg = (tid >> 4) & 31, h = tid >> 9;
            const h2v* Wk = QKB + ((2 + h)*65)*16 + ck;
            const h2v* c0p = (const h2v*)(comball + (jg*4 + 0)*144);
            const h2v* c1p = (const h2v*)(comball + (jg*4 + 1)*144);
            const h2v* c2p = (const h2v*)(comball + (jg*4 + 2)*144);
            const h2v* c3p = (const h2v*)(comball + (jg*4 + 3)*144);
            float kbv = kb[h*CK_ + ck];
            float a0 = kbv, a1 = kbv, a2 = kbv, a3 = kbv;
#pragma unroll 5
            for (int c2 = 0; c2 < 65; ++c2) {
                h2v w = Wk[c2*16];
                a0 = fdot2(c0p[c2], w, a0);
                a1 = fdot2(c1p[c2], w, a1);
                a2 = fdot2(c2p[c2], w, a2);
                a3 = fdot2(c3p[c2], w, a3);
            }
            kall[(h*128 + jg*4 + 0)*18 + ck] = (_Float16)a0;
            kall[(h*128 + jg*4 + 1)*18 + ck] = (_Float16)a1;
            kall[(h*128 + jg*4 + 2)*18 + ck] = (_Float16)a2;
            kall[(h*128 + jg*4 + 3)*18 + ck] = (_Float16)a3;
        }
        __syncthreads();
        // ---- P4: scores ----
        {
            int j = tid & 127, q4 = (tid >> 7) & 3, h = tid >> 9;
            const h2v* kp = (const h2v*)(kall + (h*128 + j)*18);
            h2v k0 = kp[0], k1 = kp[1], k2 = kp[2], k3 = kp[3],
                k4 = kp[4], k5 = kp[5], k6 = kp[6], k7 = kp[7];
            float mj = maskL[j];
#pragma unroll
            for (int ii = 0; ii < 4; ++ii) {
                int i = q4*4 + ii, ig = n0 + i;
                const h2v* qp = (const h2v*)(qfH + (h*16 + i)*18);
                float acc = 0.f;
                acc = fdot2(qp[0], k0, acc); acc = fdot2(qp[1], k1, acc);
                acc = fdot2(qp[2], k2, acc); acc = fdot2(qp[3], k3, acc);
                acc = fdot2(qp[4], k4, acc); acc = fdot2(qp[5], k5, acc);
                acc = fdot2(qp[6], k6, acc); acc = fdot2(qp[7], k7, acc);
                acc *= 0.25f;
                acc = acc > 0.f ? acc : 0.2f*acc;
                if (ig != j && (maskL[ig] == 0.f || mj == 0.f)) acc = -60000.f;
                sPH[(h*16 + i)*136 + j] = (_Float16)acc;
            }
        }
        __syncthreads();
        // ---- P5: softmax (16 waves x 2 rows) ----
        {
            int wave = tid >> 6, lane = tid & 63;
#pragma unroll
            for (int r = 0; r < 2; ++r) {
                int u = wave*2 + r;
                float x0 = (float)sPH[u*136 + lane], x1 = (float)sPH[u*136 + lane + 64];
                float m = fmaxf(x0, x1);
                for (int off = 32; off > 0; off >>= 1) m = fmaxf(m, __shfl_xor(m, off, 64));
                float e0 = __expf(x0 - m), e1 = __expf(x1 - m);
                float s = e0 + e1;
                for (int off = 32; off > 0; off >>= 1) s += __shfl_xor(s, off, 64);
                float inv = 1.f / s;
                sPH[u*136 + lane] = (_Float16)(e0*inv);
                sPH[u*136 + lane + 64] = (_Float16)(e1*inv);
            }
        }
        __syncthreads();
        // ---- P6: z[i][h*132+c] = sum_j P[h*16+i][j]*comb[j][c] via MFMA ----
        // A = sPH [32 x 128], B = comball cols [128 x 144], D tiles 2m x 9n, K=4x32
        {
            if (tid < 384) {                                 // bias row + zero pad
                int i = tid / 24, cc = tid % 24;
                z_lds[i*296 + 264 + cc] = (cc == 0) ? (_Float16)1.0f : (_Float16)0.0f;
            }
            int wv = tid >> 6, l = tid & 63, lr = l & 15, lg = l >> 4;
            for (int tile = wv; tile < 18; tile += 16) {
                int m = tile / 9, n = tile % 9;
                f4 acc = {0.f, 0.f, 0.f, 0.f};
                const _Float16* Arow = sPH + (m*16 + lr)*136 + lg*8;
                const _Float16* Bcol = comball + (lg*8)*144 + n*16 + lr;
#pragma unroll
                for (int kt = 0; kt < 4; ++kt) {
                    h8 a = *(const h8*)(Arow + kt*32);
                    h8 bf;
#pragma unroll
                    for (int j = 0; j < 8; ++j) bf[j] = Bcol[(kt*32 + j)*144];
                    acc = __builtin_amdgcn_mfma_f32_16x16x32_f16(a, bf, acc, 0, 0, 0);
                }
                int cz = n*16 + lr;
                if (cz < 132) {
#pragma unroll
                    for (int r = 0; r < 4; ++r)
                        z_lds[(lg*4 + r)*296 + m*132 + cz] = (_Float16)acc[r];
                }
            }
        }
        __syncthreads();
        // ---- P7: att[i][c'] = z @ VB3 via MFMA (bias+0.5 folded into B) ----
        // A = z_lds [16 x 288], B frags precomputed, 9 n-tiles, K=9x32
        {
            int wv = tid >> 6, l = tid & 63, lr = l & 15, lg = l >> 4;
            if (wv < 9) {
                const h8* VB = VB3 + (size_t)wv*9*64 + l;
                f4 acc = {0.f, 0.f, 0.f, 0.f};
                const _Float16* Az = z_lds + lr*296 + lg*8;
#pragma unroll
                for (int kt = 0; kt < 9; ++kt) {
                    h8 a = *(const h8*)(Az + kt*32);
                    h8 bf = VB[kt*64];
                    acc = __builtin_amdgcn_mfma_f32_16x16x32_f16(a, bf, acc, 0, 0, 0);
                }
                int cp = wv*16 + lr;
                if (cp < 132) {
#pragma unroll
                    for (int r = 0; r < 4; ++r)
                        attF[(lg*4 + r)*136 + cp] = (_Float16)acc[r];
                }
            }
        }
        __syncthreads();
        // ---- P8: R,U gates; h1 ----
        int il = tid >> 6, o = tid & 63, n = n0 + il;
        float uu, h1;
        bool ob;
        {
            const h2v* WR = WB + ((0*128 + n)*65)*64 + o;
            const h2v* WU = WB + ((1*128 + n)*65)*64 + o;
            float aR = ws[OFF_BE + (0*128 + n)*64 + o];
            float aU = ws[OFF_BE + (1*128 + n)*64 + o];
            const h2v* ar = (const h2v*)(attF + il*136);
#pragma unroll 5
            for (int c2 = 0; c2 < 65; ++c2) {
                h2v a2 = ar[c2];
                aR = fdot2(a2, WR[(size_t)c2*64], aR);
                aU = fdot2(a2, WU[(size_t)c2*64], aU);
            }
            float rg = 1.f/(1.f + __expf(-aR));
            uu = 1.f/(1.f + __expf(-aU));
            ob = maskL[n] > 0.f;
            float h0 = h_own[il*64 + o];
            h1 = ob ? rg*h0 : h0;
            h1L[il*66 + o] = h1;
        }
        __syncthreads();
        // ---- P8.5: candin = [x | h1] packed pairs (overlays z_lds) ----
        {
#pragma unroll
            for (int p = 0; p < 2; ++p) {
                int idx = tid + p*1024;
                if (idx < 1040) {
                    int il2 = idx / 65, cw = idx % 65;
                    int c0 = 2*cw, c1 = 2*cw + 1;
                    int j = n0 + il2;
                    float v0 = (c0 < 65) ? (float)comball[j*144 + c0]
                                         : h1L[il2*66 + c0 - 65];
                    float v1 = (c1 < 65) ? (float)comball[j*144 + c1]
                             : ((c1 <= 128) ? h1L[il2*66 + c1 - 65] : 0.f);
                    candin[il2*66 + cw] = h2v{(_Float16)v0, (_Float16)v1};
                }
            }
        }
        __syncthreads();
        // ---- P9: candidate; h2; export ----
        {
            const h2v* WC = WB + ((2*128 + n)*65)*64 + o;
            float aC = ws[OFF_BE + (2*128 + n)*64 + o];
            const h2v* zr = candin + il*66;
#pragma unroll 5
            for (int c2 = 0; c2 < 65; ++c2)
                aC = fdot2(zr[c2], WC[(size_t)c2*64], aC);
            float cand = tanhf(aC);
            float h2 = ob ? (1.f - uu)*h1 + uu*cand : h1;
            h_own[il*64 + o] = h2;
            if (t == lenb - 1) out[(size_t)(b*N_ + n)*64 + o] = h2;
            if (t < T_ - 1) {
                float* Hw = Hx + (size_t)(((t + 1) & 1)*B_ + b)*N_*64 + (n0 + il)*64 + o;
                __hip_atomic_store(Hw, h2, __ATOMIC_RELAXED, __HIP_MEMORY_SCOPE_AGENT);
            }
        }
        __syncthreads();    // drains stores (compiler emits vmcnt(0) before s_barrier)
        if (t < T_ - 1 && tid == 0)
            __hip_atomic_fetch_add(&CNT[b], 1u, __ATOMIC_RELAXED, __HIP_MEMORY_SCOPE_AGENT);
    }
}

extern "C" void kernel_launch(void* const* d_in, const int* in_sizes, int n_in,
                              void* d_out, int out_size, void* d_ws, size_t ws_size,
                              hipStream_t stream) {
    (void)in_sizes; (void)n_in; (void)out_size; (void)ws_size;
    const float* obs   = (const float*)d_in[0];
    const float* mask  = (const float*)d_in[1];
    const float* avg   = (const float*)d_in[2];
    const float* plm   = (const float*)d_in[3];
    const int*   lens  = (const int*)d_in[4];
    // d_in[5] rarity_W: only the ==0 pattern of cur_adj matters -> dead values
    const float* pfW1  = (const float*)d_in[6];
    const float* pfb1  = (const float*)d_in[7];
    const float* pfW2  = (const float*)d_in[8];
    const float* pfb2  = (const float*)d_in[9];
    // d_in[10..13] pg_*: dead (softmax adjacency > 0 always)
    const float* rstW  = (const float*)d_in[14];
    const float* rstb  = (const float*)d_in[15];
    const float* updW  = (const float*)d_in[16];
    const float* updb  = (const float*)d_in[17];
    const float* candW = (const float*)d_in[18];
    const float* candb = (const float*)d_in[19];
    const float* qW    = (const float*)d_in[20];
    const float* qb    = (const float*)d_in[21];
    const float* kW    = (const float*)d_in[22];
    const float* kb    = (const float*)d_in[23];
    const float* vW    = (const float*)d_in[24];
    const float* vb    = (const float*)d_in[25];
    float* ws  = (float*)d_ws;
    float* out = (float*)d_out;

    hipMemsetAsync((char*)d_ws + (size_t)OFF_CNT*4, 0, 32*sizeof(unsigned), stream);
    hipLaunchKernelGGL(k_qv,   dim3(128), dim3(128), 0, stream, plm, pfW1, pfb1, pfW2, pfb2, ws);
    hipLaunchKernelGGL(k_weff, dim3(384), dim3(256), 0, stream, rstW, updW, candW, rstb, updb, candb, ws);
    hipLaunchKernelGGL(k_pack, dim3(64),  dim3(256), 0, stream, vW, qW, kW, vb, ws);
    hipLaunchKernelGGL(k_vto,  dim3(16),  dim3(256), 0, stream, mask, ws);

    void* args[] = {(void*)&obs, (void*)&mask, (void*)&avg, (void*)&lens,
                    (void*)&qb, (void*)&kb, (void*)&ws, (void*)&out};
    hipLaunchCooperativeKernel((void*)k_main, dim3(256), dim3(1024), args, 0, stream);
}

// Round 2
// 1759.358 us; speedup vs baseline: 2.1114x; 1.2808x over previous
//
#include <hip/hip_runtime.h>
#include <math.h>

#define B_   32
#define T_   64
#define N_   128
#define D_   64
#define C_   129
#define CK_  16
#define H_   2
#define QD_  5
#define PLM_ 768

typedef _Float16 h2v __attribute__((ext_vector_type(2)));
typedef _Float16 h4v __attribute__((ext_vector_type(4)));
typedef _Float16 h8  __attribute__((ext_vector_type(8)));
typedef float    f4  __attribute__((ext_vector_type(4)));

// ---- workspace layout (float/u32 slots) ----
constexpr int OFF_QV   = 0;                           // 640
constexpr int OFF_BE   = 640;                         // fp32 3*128*64
constexpr int OFF_WB2  = OFF_BE + 3*128*64;           // h2v 3*128*65*64 gate weights [g][n][c2][o], pair over c'
constexpr int OFF_VWB2 = OFF_WB2 + 3*128*65*64;       // (dead) h2v 2*65*132
constexpr int OFF_QKB2 = OFF_VWB2 + 2*65*132;         // (dead) h2v 4*65*16
constexpr int OFF_ATTB = OFF_QKB2 + 4*65*16;          // (dead) fp32 132
constexpr int OFF_VTO  = OFF_ATTB + 132;              // fp32 B*N
constexpr int OFF_H    = OFF_VTO + B_*N_;             // fp32 2*B*N*64 double-buffered h exchange
constexpr int OFF_CNT  = OFF_H + 2*B_*N_*64;          // u32 x32 barrier counters (memset 0 per launch)
constexpr int OFF_VWB3 = OFF_CNT + 32;                // f16 9*9*64*8 att-GEMM B-fragments (frag-major)
constexpr int OFF_QKB4 = OFF_VWB3 + 9*9*64*8/2;       // f16 2*2*4*64*8 q/k-GEMM B-frags [qk][h][kt][l][j]
constexpr int OFF_QKE  = OFF_QKB4 + 2*2*4*64*8/2;     // f32 2*2*2*16: [qk][h][{w_c128,bias}][ck]

#if __has_builtin(__builtin_amdgcn_fdot2)
__device__ __forceinline__ float fdot2(h2v a, h2v b, float c) {
    return __builtin_amdgcn_fdot2(a, b, c, false);
}
#else
__device__ __forceinline__ float fdot2(h2v a, h2v b, float c) {
    return c + (float)a.x*(float)b.x + (float)a.y*(float)b.y;
}
#endif

// ---------------- precompute kernels ----------------

__global__ void k_qv(const float* __restrict__ plm, const float* __restrict__ W1,
                     const float* __restrict__ b1, const float* __restrict__ W2,
                     const float* __restrict__ b2, float* __restrict__ ws) {
    int n = blockIdx.x, j = threadIdx.x;          // 128 x 128
    __shared__ float hid[128];
    float acc = b1[j];
    for (int p = 0; p < PLM_; ++p) acc += plm[n*PLM_ + p] * W1[p*128 + j];
    hid[j] = fmaxf(acc, 0.f);
    __syncthreads();
    if (j < QD_) {
        float a = b2[j];
        for (int q = 0; q < 128; ++q) a += hid[q] * W2[q*QD_ + j];
        ws[OFF_QV + n*QD_ + j] = a;
    }
}

// WB2[g][n][c2][o] = h2v( Weff[c'=2c2][o], Weff[2c2+1][o] );  BE[g][n][o]
__global__ void k_weff(const float* __restrict__ rW, const float* __restrict__ uW,
                       const float* __restrict__ cW, const float* __restrict__ rb,
                       const float* __restrict__ ub, const float* __restrict__ cb,
                       float* __restrict__ ws) {
    int g = blockIdx.x >> 7, n = blockIdx.x & 127;   // 384 blocks x 256 thr
    const float* W  = (g == 0) ? rW : (g == 1) ? uW : cW;
    const float* bb = (g == 0) ? rb : (g == 1) ? ub : cb;
    float qn[QD_];
#pragma unroll
    for (int q = 0; q < QD_; ++q) qn[q] = ws[OFF_QV + n*QD_ + q];
    h2v* WB = (h2v*)(ws + OFF_WB2);
    for (int idx = threadIdx.x; idx < 65*64; idx += 256) {
        int c2 = idx >> 6, o = idx & 63;
        float w0 = 0.f, w1 = 0.f;
#pragma unroll
        for (int q = 0; q < QD_; ++q) w0 += qn[q] * W[(q*C_ + 2*c2)*D_ + o];
        if (2*c2 + 1 < C_) {
#pragma unroll
            for (int q = 0; q < QD_; ++q) w1 += qn[q] * W[(q*C_ + 2*c2 + 1)*D_ + o];
        }
        WB[((g*128 + n)*65 + c2)*64 + o] = h2v{(_Float16)w0, (_Float16)w1};
    }
    if (threadIdx.x < D_) {
        int o = threadIdx.x;
        float acc = 0.f;
#pragma unroll
        for (int q = 0; q < QD_; ++q) acc += qn[q] * bb[q*D_ + o];
        ws[OFF_BE + (g*128 + n)*D_ + o] = acc;
    }
}

// VWB3 att-GEMM B frags: lane l elem j = B[k=kt*32+(l>>4)*8+j][n=nt*16+(l&15)]
//   B[k][n] = 0.5*vW[h=k/132][c=k%132][n]  (k<264, c<129, n<129)
//   B[264][n] = 0.5*(vb0[n]+vb1[n]);  else 0.
// QKB4 q/k-GEMM B frags over K=c (c<128): idx = ((((qk*2+h)*4+kt)*64)+l)*8+j
//   val = srcW[h][c = kt*32+((l>>4)&3)*8+j][ck = l&15]
// QKE: [qk][h][0][ck] = srcW[h][128][ck];  [qk][h][1][ck] = bias[h][ck]
__global__ void k_pack(const float* __restrict__ vW, const float* __restrict__ qW,
                       const float* __restrict__ kW, const float* __restrict__ vb,
                       const float* __restrict__ qb, const float* __restrict__ kb,
                       float* __restrict__ ws) {
    int stride = gridDim.x * blockDim.x;
    int t0 = blockIdx.x * blockDim.x + threadIdx.x;
    _Float16* VB = (_Float16*)(ws + OFF_VWB3);
    for (int idx = t0; idx < 9*9*64*8; idx += stride) {
        int j  = idx & 7;
        int l  = (idx >> 3) & 63;
        int rest = idx >> 9;           // nt*9 + kt
        int kt = rest % 9, nt = rest / 9;
        int k = kt*32 + (l >> 4)*8 + j;
        int n = nt*16 + (l & 15);
        float v = 0.f;
        if (n < C_) {
            if (k < 264) {
                int h = k / 132, c = k % 132;
                if (c < C_) v = 0.5f * vW[(h*C_ + c)*C_ + n];
            } else if (k == 264) {
                v = 0.5f * (vb[n] + vb[C_ + n]);
            }
        }
        VB[idx] = (_Float16)v;
    }
    _Float16* QK4 = (_Float16*)(ws + OFF_QKB4);
    for (int idx = t0; idx < 2*2*4*64*8; idx += stride) {
        int j = idx & 7, l = (idx >> 3) & 63, kt = (idx >> 9) & 3;
        int h = (idx >> 11) & 1, qk = (idx >> 12) & 1;
        int c = kt*32 + ((l >> 4) & 3)*8 + j, ck = l & 15;
        const float* src = qk ? qW : kW;
        QK4[idx] = (_Float16)src[(h*C_ + c)*CK_ + ck];
    }
    float* QE = ws + OFF_QKE;
    for (int idx = t0; idx < 128; idx += stride) {
        int ck = idx & 15, kind = (idx >> 4) & 1, h = (idx >> 5) & 1, qk = (idx >> 6) & 1;
        const float* src = qk ? qW : kW;
        const float* sb  = qk ? qb : kb;
        QE[idx] = kind ? sb[h*CK_ + ck] : src[(h*C_ + 128)*CK_ + ck];
    }
}

__global__ void k_vto(const float* __restrict__ mask, float* __restrict__ ws) {
    int idx = blockIdx.x * blockDim.x + threadIdx.x;
    if (idx < B_*N_) {
        int b = idx >> 7, n = idx & 127;
        float acc = 0.f;
        for (int t = 0; t < T_; ++t) acc += mask[(b*T_ + t)*N_ + n];
        ws[OFF_VTO + idx] = acc;
    }
}

// ---------------- main recurrent kernel ----------------
// 256 blocks x 1024 threads, cooperative (co-residency only, NO grid.sync).
// block = (b = blk>>3, ng = blk&7 : 16 nodes). Only h crosses blocks.
// q/k/scores (comb@qkW, q@k^T), z (P@comb) and att (z@vW) on MFMA; rest VALU.
__global__ void __launch_bounds__(1024, 4) k_main(
    const float* __restrict__ obs, const float* __restrict__ mask,
    const float* __restrict__ avg, const int* __restrict__ lengths,
    const float* __restrict__ qb, const float* __restrict__ kb,
    float* __restrict__ ws, float* __restrict__ out) {
    const int tid = threadIdx.x;
    const int b  = blockIdx.x >> 3;
    const int ng = blockIdx.x & 7;
    const int n0 = ng * 16;

    // LDS: 36864 + 8704 + 13824 + 512 + 4096 = 64000 B  (<= 64 KB)
    __shared__ __align__(16) _Float16 comball[128*144]; // [j][c]: 0..63 obs,64 rar,65..128 h,129..143 pad0
    __shared__ __align__(16) char regA[8704];  // sPH f16[32][136] -> { attF f16[16][136] @0 | h1L f32[16*66] @4352 }
    __shared__ __align__(16) char regB[13824]; // kall f16[2*128][24] @0 + qf f16[2*16][24] @12288 -> z_lds f16[16][296] -> candin h2v[16*66]
    __shared__ float maskL[128];
    __shared__ float h_own[16*64];

    _Float16* sPH    = (_Float16*)regA;              // [32][136]
    _Float16* attF   = (_Float16*)regA;              // [16][136]
    float*    h1L    = (float*)(regA + 4352);        // [16][66]
    _Float16* kall   = (_Float16*)regB;              // [2*128][24]
    _Float16* qf     = (_Float16*)(regB + 12288);    // [2*16][24]
    _Float16* z_lds  = (_Float16*)regB;              // [16][296]: cols 0..263 z, 264 bias=1, 265..287 zero
    h2v*      candin = (h2v*)regB;                   // [16][66]

    float* Hx = ws + OFF_H;
    unsigned* CNT = (unsigned*)(ws + OFF_CNT);
    const h2v* WB  = (const h2v*)(ws + OFF_WB2);
    const h8*  VB3 = (const h8*)(ws + OFF_VWB3);
    const h8*  QK4 = (const h8*)(ws + OFF_QKB4);

    for (int i = tid; i < 16*64; i += 1024) h_own[i] = 0.f;
    for (int i = tid; i < 128*15; i += 1024)                  // zero pad cols 129..143
        comball[(i/15)*144 + 129 + (i%15)] = (_Float16)0.f;
    const int lenb = lengths[b];
    __syncthreads();

    for (int t = 0; t < T_; ++t) {
        // ---- P0: barrier + import h ----
        if (t > 0) {
            if (tid == 0) {
                unsigned target = 8u * (unsigned)t;
                while (__hip_atomic_load(&CNT[b], __ATOMIC_RELAXED,
                                         __HIP_MEMORY_SCOPE_AGENT) < target)
                    __builtin_amdgcn_s_sleep(2);
            }
            __syncthreads();
            const float* Hr = Hx + (size_t)((t & 1)*B_ + b)*N_*64;
#pragma unroll
            for (int p = 0; p < 8; ++p) {
                int idx = tid + p*1024;
                int j = idx >> 6, d = idx & 63;
                float hv = ((j >> 4) == ng) ? h_own[(j & 15)*64 + d]
                         : __hip_atomic_load((float*)Hr + idx, __ATOMIC_RELAXED,
                                             __HIP_MEMORY_SCOPE_AGENT);
                comball[j*144 + 65 + d] = (_Float16)hv;
            }
        } else {
#pragma unroll
            for (int p = 0; p < 8; ++p) {
                int idx = tid + p*1024;
                comball[(idx >> 6)*144 + 65 + (idx & 63)] = (_Float16)0.f;
            }
        }
        // ---- P1: x-part ----
        {
            const float* obsR = obs + (size_t)(b*T_ + t)*N_*D_;
#pragma unroll
            for (int p = 0; p < 8; ++p) {
                int idx = tid + p*1024;
                comball[(idx >> 6)*144 + (idx & 63)] = (_Float16)obsR[idx];
            }
            if (tid < 128) {
                maskL[tid] = mask[(b*T_ + t)*N_ + tid];
                float a = avg[(b*T_ + t)*N_ + tid];
                comball[tid*144 + 64] =
                    (_Float16)(0.5f * tanhf(a / (ws[OFF_VTO + b*N_ + tid] + 1.f)));
            }
        }
        __syncthreads();
        // ---- P2/3: q (own 16 nodes) + k (all 128) via MFMA 16x16x32 ----
        // k_h = comb @ kW_h : 16 jobs (h x mtile); q_h = comb[own] @ qW_h : 2 jobs.
        // K-tiles cover c=0..127; c=128 column + bias added in epilogue (QKE).
        {
            int w = tid >> 6, l = tid & 63, lr = l & 15, lg = l >> 4;
            int nj = (w < 2) ? 2 : 1;
            for (int jb = 0; jb < nj; ++jb) {
                int qk = jb;                          // 0 = k-weights, 1 = q-weights
                int hh = jb ? w : (w >> 3);
                int rbase = jb ? n0 : (w & 7)*16;
                const h8* Wf = QK4 + ((qk*2 + hh)*4)*64 + l;
                const _Float16* Ab = comball + (rbase + lr)*144;
                f4 acc = {0.f, 0.f, 0.f, 0.f};
#pragma unroll
                for (int kt = 0; kt < 4; ++kt) {
                    h8 a = *(const h8*)(Ab + kt*32 + lg*8);
                    h8 bf = Wf[kt*64];
                    acc = __builtin_amdgcn_mfma_f32_16x16x32_f16(a, bf, acc, 0, 0, 0);
                }
                const float* QE = ws + OFF_QKE + (qk*2 + hh)*32;
                float w128 = QE[lr], wbias = QE[16 + lr];
#pragma unroll
                for (int r = 0; r < 4; ++r) {
                    int row = rbase + lg*4 + r;
                    float v = acc[r] + (float)comball[row*144 + 128] * w128 + wbias;
                    if (jb == 0) kall[(hh*128 + row)*24 + lr] = (_Float16)v;
                    else         qf[(hh*16 + lg*4 + r)*24 + lr] = (_Float16)v;
                }
            }
        }
        __syncthreads();
        // ---- P4: scores via MFMA (K=16 zero-padded to 32) ----
        {
            int w = tid >> 6, l = tid & 63, lr = l & 15, lg = l >> 4;
            int h = w >> 3, nt = w & 7;
            h8 a = {}, bq = {};
            if (lg < 2) {
                a  = *(const h8*)(qf + (h*16 + lr)*24 + lg*8);
                bq = *(const h8*)(kall + (h*128 + nt*16 + lr)*24 + lg*8);
            }
            f4 s4 = {0.f, 0.f, 0.f, 0.f};
            s4 = __builtin_amdgcn_mfma_f32_16x16x32_f16(a, bq, s4, 0, 0, 0);
            int j = nt*16 + lr;
            float mj = maskL[j];
#pragma unroll
            for (int r = 0; r < 4; ++r) {
                int i = lg*4 + r, ig = n0 + i;
                float v = s4[r] * 0.25f;
                v = v > 0.f ? v : 0.2f*v;
                if (ig != j && (maskL[ig] == 0.f || mj == 0.f)) v = -60000.f;
                sPH[(h*16 + i)*136 + j] = (_Float16)v;
            }
        }
        __syncthreads();
        // ---- P5: softmax (16 waves x 2 rows) ----
        {
            int wave = tid >> 6, lane = tid & 63;
#pragma unroll
            for (int r = 0; r < 2; ++r) {
                int u = wave*2 + r;
                float x0 = (float)sPH[u*136 + lane], x1 = (float)sPH[u*136 + lane + 64];
                float m = fmaxf(x0, x1);
                for (int off = 32; off > 0; off >>= 1) m = fmaxf(m, __shfl_xor(m, off, 64));
                float e0 = __expf(x0 - m), e1 = __expf(x1 - m);
                float s = e0 + e1;
                for (int off = 32; off > 0; off >>= 1) s += __shfl_xor(s, off, 64);
                float inv = 1.f / s;
                sPH[u*136 + lane] = (_Float16)(e0*inv);
                sPH[u*136 + lane + 64] = (_Float16)(e1*inv);
            }
        }
        __syncthreads();
        // ---- P6: z[i][h*132+c] = sum_j P[h*16+i][j]*comb[j][c] via MFMA ----
        // A = sPH [32 x 128], B = comball cols [128 x 144], D tiles 2m x 9n, K=4x32
        {
            if (tid < 384) {                                 // bias row + zero pad
                int i = tid / 24, cc = tid % 24;
                z_lds[i*296 + 264 + cc] = (cc == 0) ? (_Float16)1.0f : (_Float16)0.0f;
            }
            int wv = tid >> 6, l = tid & 63, lr = l & 15, lg = l >> 4;
            for (int tile = wv; tile < 18; tile += 16) {
                int m = tile / 9, n = tile % 9;
                f4 acc = {0.f, 0.f, 0.f, 0.f};
                const _Float16* Arow = sPH + (m*16 + lr)*136 + lg*8;
                const _Float16* Bcol = comball + (lg*8)*144 + n*16 + lr;
#pragma unroll
                for (int kt = 0; kt < 4; ++kt) {
                    h8 a = *(const h8*)(Arow + kt*32);
                    h8 bf;
#pragma unroll
                    for (int j = 0; j < 8; ++j) bf[j] = Bcol[(kt*32 + j)*144];
                    acc = __builtin_amdgcn_mfma_f32_16x16x32_f16(a, bf, acc, 0, 0, 0);
                }
                int cz = n*16 + lr;
                if (cz < 132) {
#pragma unroll
                    for (int r = 0; r < 4; ++r)
                        z_lds[(lg*4 + r)*296 + m*132 + cz] = (_Float16)acc[r];
                }
            }
        }
        __syncthreads();
        // ---- P7: att[i][c'] = z @ VB3 via MFMA (bias+0.5 folded into B) ----
        // A = z_lds [16 x 288], B frags precomputed, 9 n-tiles, K=9x32
        {
            int wv = tid >> 6, l = tid & 63, lr = l & 15, lg = l >> 4;
            if (wv < 9) {
                const h8* VB = VB3 + (size_t)wv*9*64 + l;
                f4 acc = {0.f, 0.f, 0.f, 0.f};
                const _Float16* Az = z_lds + lr*296 + lg*8;
#pragma unroll
                for (int kt = 0; kt < 9; ++kt) {
                    h8 a = *(const h8*)(Az + kt*32);
                    h8 bf = VB[kt*64];
                    acc = __builtin_amdgcn_mfma_f32_16x16x32_f16(a, bf, acc, 0, 0, 0);
                }
                int cp = wv*16 + lr;
                if (cp < 132) {
#pragma unroll
                    for (int r = 0; r < 4; ++r)
                        attF[(lg*4 + r)*136 + cp] = (_Float16)acc[r];
                }
            }
        }
        __syncthreads();
        // ---- P8: R,U gates; h1 ----
        int il = tid >> 6, o = tid & 63, n = n0 + il;
        float uu, h1;
        bool ob;
        {
            const h2v* WR = WB + ((0*128 + n)*65)*64 + o;
            const h2v* WU = WB + ((1*128 + n)*65)*64 + o;
            float aR = ws[OFF_BE + (0*128 + n)*64 + o];
            float aU = ws[OFF_BE + (1*128 + n)*64 + o];
            const h2v* ar = (const h2v*)(attF + il*136);
#pragma unroll 5
            for (int c2 = 0; c2 < 65; ++c2) {
                h2v a2 = ar[c2];
                aR = fdot2(a2, WR[(size_t)c2*64], aR);
                aU = fdot2(a2, WU[(size_t)c2*64], aU);
            }
            float rg = 1.f/(1.f + __expf(-aR));
            uu = 1.f/(1.f + __expf(-aU));
            ob = maskL[n] > 0.f;
            float h0 = h_own[il*64 + o];
            h1 = ob ? rg*h0 : h0;
            h1L[il*66 + o] = h1;
        }
        __syncthreads();
        // ---- P8.5: candin = [x | h1] packed pairs (overlays z_lds) ----
        {
#pragma unroll
            for (int p = 0; p < 2; ++p) {
                int idx = tid + p*1024;
                if (idx < 1040) {
                    int il2 = idx / 65, cw = idx % 65;
                    int c0 = 2*cw, c1 = 2*cw + 1;
                    int j = n0 + il2;
                    float v0 = (c0 < 65) ? (float)comball[j*144 + c0]
                                         : h1L[il2*66 + c0 - 65];
                    float v1 = (c1 < 65) ? (float)comball[j*144 + c1]
                             : ((c1 <= 128) ? h1L[il2*66 + c1 - 65] : 0.f);
                    candin[il2*66 + cw] = h2v{(_Float16)v0, (_Float16)v1};
                }
            }
        }
        __syncthreads();
        // ---- P9: candidate; h2; export ----
        {
            const h2v* WC = WB + ((2*128 + n)*65)*64 + o;
            float aC = ws[OFF_BE + (2*128 + n)*64 + o];
            const h2v* zr = candin + il*66;
#pragma unroll 5
            for (int c2 = 0; c2 < 65; ++c2)
                aC = fdot2(zr[c2], WC[(size_t)c2*64], aC);
            float cand = tanhf(aC);
            float h2 = ob ? (1.f - uu)*h1 + uu*cand : h1;
            h_own[il*64 + o] = h2;
            if (t == lenb - 1) out[(size_t)(b*N_ + n)*64 + o] = h2;
            if (t < T_ - 1) {
                float* Hw = Hx + (size_t)(((t + 1) & 1)*B_ + b)*N_*64 + (n0 + il)*64 + o;
                __hip_atomic_store(Hw, h2, __ATOMIC_RELAXED, __HIP_MEMORY_SCOPE_AGENT);
            }
        }
        __syncthreads();    // drains stores (compiler emits vmcnt(0) before s_barrier)
        if (t < T_ - 1 && tid == 0)
            __hip_atomic_fetch_add(&CNT[b], 1u, __ATOMIC_RELAXED, __HIP_MEMORY_SCOPE_AGENT);
    }
}

extern "C" void kernel_launch(void* const* d_in, const int* in_sizes, int n_in,
                              void* d_out, int out_size, void* d_ws, size_t ws_size,
                              hipStream_t stream) {
    (void)in_sizes; (void)n_in; (void)out_size; (void)ws_size;
    const float* obs   = (const float*)d_in[0];
    const float* mask  = (const float*)d_in[1];
    const float* avg   = (const float*)d_in[2];
    const float* plm   = (const float*)d_in[3];
    const int*   lens  = (const int*)d_in[4];
    // d_in[5] rarity_W: only the ==0 pattern of cur_adj matters -> dead values
    const float* pfW1  = (const float*)d_in[6];
    const float* pfb1  = (const float*)d_in[7];
    const float* pfW2  = (const float*)d_in[8];
    const float* pfb2  = (const float*)d_in[9];
    // d_in[10..13] pg_*: dead (softmax adjacency > 0 always)
    const float* rstW  = (const float*)d_in[14];
    const float* rstb  = (const float*)d_in[15];
    const float* updW  = (const float*)d_in[16];
    const float* updb  = (const float*)d_in[17];
    const float* candW = (const float*)d_in[18];
    const float* candb = (const float*)d_in[19];
    const float* qW    = (const float*)d_in[20];
    const float* qb    = (const float*)d_in[21];
    const float* kW    = (const float*)d_in[22];
    const float* kb    = (const float*)d_in[23];
    const float* vW    = (const float*)d_in[24];
    const float* vb    = (const float*)d_in[25];
    float* ws  = (float*)d_ws;
    float* out = (float*)d_out;

    hipMemsetAsync((char*)d_ws + (size_t)OFF_CNT*4, 0, 32*sizeof(unsigned), stream);
    hipLaunchKernelGGL(k_qv,   dim3(128), dim3(128), 0, stream, plm, pfW1, pfb1, pfW2, pfb2, ws);
    hipLaunchKernelGGL(k_weff, dim3(384), dim3(256), 0, stream, rstW, updW, candW, rstb, updb, candb, ws);
    hipLaunchKernelGGL(k_pack, dim3(64),  dim3(256), 0, stream, vW, qW, kW, vb, qb, kb, ws);
    hipLaunchKernelGGL(k_vto,  dim3(16),  dim3(256), 0, stream, mask, ws);

    void* args[] = {(void*)&obs, (void*)&mask, (void*)&avg, (void*)&lens,
                    (void*)&qb, (void*)&kb, (void*)&ws, (void*)&out};
    hipLaunchCooperativeKernel((void*)k_main, dim3(256), dim3(1024), args, 0, stream);
}